// Round 1
// baseline (861.660 us; speedup 1.0000x reference)
//
#include <hip/hip_runtime.h>
#include <hip/hip_bf16.h>

typedef __hip_bfloat16 bf16;
typedef __attribute__((ext_vector_type(4))) float floatx4;
typedef __attribute__((ext_vector_type(8))) short shortx8;

#define MFMA16(a, b, c) __builtin_amdgcn_mfma_f32_16x16x32_bf16(a, b, c, 0, 0, 0)

// ---------------------------------------------------------------------------
// fp32 -> bf16 convert, 4 elems/thread, n % 1024 == 0
// ---------------------------------------------------------------------------
__global__ __launch_bounds__(256) void f2b_kernel(const float* __restrict__ in,
                                                  bf16* __restrict__ out, int n) {
  int i = (blockIdx.x * 256 + threadIdx.x) * 4;
  if (i < n) {
    float4 v = *(const float4*)(in + i);
    bf16 h0 = __float2bfloat16(v.x), h1 = __float2bfloat16(v.y);
    bf16 h2 = __float2bfloat16(v.z), h3 = __float2bfloat16(v.w);
    ushort4 u;
    u.x = __builtin_bit_cast(unsigned short, h0);
    u.y = __builtin_bit_cast(unsigned short, h1);
    u.z = __builtin_bit_cast(unsigned short, h2);
    u.w = __builtin_bit_cast(unsigned short, h3);
    *(ushort4*)(out + i) = u;
  }
}

// ---------------------------------------------------------------------------
// NT GEMM: C[n,m] = A[n,:] . W[m,:]  (A [N,K] bf16, W [M,K] bf16, both K-major)
// 128x128 tile, 4 waves (2x2), each wave 64x64 via 4x4 of 16x16x32 MFMA.
// EPI: 0 = phi(x)=elu(x)+1 -> bf16 ; 1 = identity -> bf16 ;
//      2 = relu -> bf16 ; 3 = + residual(fp32) -> fp32
// ---------------------------------------------------------------------------
template <int EPI>
__global__ __launch_bounds__(256, 2) void gemm_nt(const bf16* __restrict__ A,
                                                  const bf16* __restrict__ Bw,
                                                  const float* __restrict__ bias,
                                                  const float* __restrict__ res,
                                                  void* __restrict__ outp,
                                                  const int M, const int K) {
  __shared__ __align__(16) bf16 sA[128][32];
  __shared__ __align__(16) bf16 sB[128][32];
  const int tid = threadIdx.x;
  const int lane = tid & 63, wave = tid >> 6;
  const int wm = wave & 1, wn = wave >> 1;
  const int bm = blockIdx.x, bn = blockIdx.y;
  floatx4 acc[4][4] = {};
  const int ar = tid >> 2;         // 0..63 staging row
  const int ak = (tid & 3) << 3;   // 0,8,16,24 staging k
  const bf16* Ab = A + (size_t)(bm * 128 + ar) * K + ak;
  const bf16* Bb = Bw + (size_t)(bn * 128 + ar) * K + ak;
  const int frow = lane & 15, fk = (lane >> 4) << 3;

  for (int k0 = 0; k0 < K; k0 += 32) {
    shortx8 a0 = *(const shortx8*)(Ab + k0);
    shortx8 a1 = *(const shortx8*)(Ab + (size_t)64 * K + k0);
    shortx8 b0 = *(const shortx8*)(Bb + k0);
    shortx8 b1 = *(const shortx8*)(Bb + (size_t)64 * K + k0);
    __syncthreads();
    *(shortx8*)&sA[ar][ak] = a0;
    *(shortx8*)&sA[ar + 64][ak] = a1;
    *(shortx8*)&sB[ar][ak] = b0;
    *(shortx8*)&sB[ar + 64][ak] = b1;
    __syncthreads();
    shortx8 af[4], bfr[4];
#pragma unroll
    for (int i = 0; i < 4; i++) af[i] = *(const shortx8*)&sA[wm * 64 + i * 16 + frow][fk];
#pragma unroll
    for (int j = 0; j < 4; j++) bfr[j] = *(const shortx8*)&sB[wn * 64 + j * 16 + frow][fk];
#pragma unroll
    for (int i = 0; i < 4; i++)
#pragma unroll
      for (int j = 0; j < 4; j++)
        acc[i][j] = MFMA16(af[i], bfr[j], acc[i][j]);
  }

  const int row0 = bm * 128 + wm * 64 + ((lane >> 4) << 2);
  const int col0 = bn * 128 + wn * 64 + (lane & 15);
#pragma unroll
  for (int j = 0; j < 4; j++) {
    const int col = col0 + j * 16;
    const float bj = bias[col];
#pragma unroll
    for (int i = 0; i < 4; i++) {
#pragma unroll
      for (int r = 0; r < 4; r++) {
        const int row = row0 + i * 16 + r;
        const size_t o = (size_t)row * M + col;
        float v = acc[i][j][r] + bj;
        if (EPI == 0) {
          v = v > 0.f ? v + 1.f : __expf(v);
          ((bf16*)outp)[o] = __float2bfloat16(v);
        } else if (EPI == 1) {
          ((bf16*)outp)[o] = __float2bfloat16(v);
        } else if (EPI == 2) {
          ((bf16*)outp)[o] = __float2bfloat16(fmaxf(v, 0.f));
        } else {
          ((float*)outp)[o] = v + res[o];
        }
      }
    }
  }
}

// ---------------------------------------------------------------------------
// context: ctx[bh,d,e] = sum_s phiK[s,b,h*64+d] * V[s,b,h*64+e]
//          ksum[bh,d]  = sum_s phiK[s,b,h*64+d]
// grid (64 bh, 8 s-chunks of 512), block 256. fp32 atomics into zeroed ws.
// ---------------------------------------------------------------------------
__global__ __launch_bounds__(256) void ctx_kernel(const bf16* __restrict__ phiK,
                                                  const bf16* __restrict__ V,
                                                  float* __restrict__ ctx,
                                                  float* __restrict__ ksum) {
  const int bh = blockIdx.x, b = bh >> 4, h = bh & 15;
  const int t = threadIdx.x;
  __shared__ float sK[8][64];
  __shared__ float sV[8][64];
  float acc[16] = {};
  float kacc = 0.f;
  const int d = t >> 2, e0 = (t & 3) << 4;
  const int rr = t >> 5, cc = (t & 31) * 2;
  const size_t headoff = (size_t)b * 1024 + h * 64;
  const int sbeg = blockIdx.y * 512;
  for (int s0 = sbeg; s0 < sbeg + 512; s0 += 8) {
    size_t g = (size_t)(s0 + rr) * 4096 + headoff + cc;
    __hip_bfloat162 kv = *(const __hip_bfloat162*)(phiK + g);
    __hip_bfloat162 vv = *(const __hip_bfloat162*)(V + g);
    __syncthreads();
    sK[rr][cc] = (float)kv.x;
    sK[rr][cc + 1] = (float)kv.y;
    sV[rr][cc] = (float)vv.x;
    sV[rr][cc + 1] = (float)vv.y;
    __syncthreads();
#pragma unroll
    for (int ss = 0; ss < 8; ss++) {
      float kd = sK[ss][d];
      kacc += kd;
#pragma unroll
      for (int ee = 0; ee < 16; ee++) acc[ee] += kd * sV[ss][e0 + ee];
    }
  }
  float* cdst = ctx + (size_t)bh * 4096 + d * 64 + e0;
#pragma unroll
  for (int ee = 0; ee < 16; ee++) atomicAdd(cdst + ee, acc[ee]);
  if ((t & 3) == 0) atomicAdd(ksum + bh * 64 + d, kacc);
}

// ---------------------------------------------------------------------------
// apply: out[s,b,h*64+e] = (sum_d phiQ[s,d]*ctx[d,e]) / (sum_d phiQ[s,d]*ksum[d] + eps)
// MFMA: A = phiQ rows (direct from global), B = ctxT in LDS (bf16),
// denominator = extra MFMA with ksum broadcast over all 16 columns.
// grid (64 bh, 32 s-chunks of 128), block 256 (4 waves x 32 rows).
// ---------------------------------------------------------------------------
__global__ __launch_bounds__(256) void attn_mfma(const bf16* __restrict__ phiQ,
                                                 const float* __restrict__ ctx,
                                                 const float* __restrict__ ksum,
                                                 bf16* __restrict__ attn) {
  __shared__ __align__(16) bf16 sctxT[64][72];  // [e][d], +8 pad keeps 16B align, 2-way banks
  __shared__ __align__(16) bf16 sks[64];
  const int bh = blockIdx.x, b = bh >> 4, h = bh & 15;
  const int t = threadIdx.x, lane = t & 63, wave = t >> 6;
  const float* cbase = ctx + (size_t)bh * 4096;
  for (int idx = t; idx < 4096; idx += 256) {
    int d = idx >> 6, e = idx & 63;
    sctxT[e][d] = __float2bfloat16(cbase[idx]);
  }
  if (t < 64) sks[t] = __float2bfloat16(ksum[bh * 64 + t]);
  __syncthreads();

  const int s0 = blockIdx.y * 128 + wave * 32;
  const int frow = lane & 15, fk = (lane >> 4) << 3;
  shortx8 bfr[2][4], kfr[2];
#pragma unroll
  for (int ks = 0; ks < 2; ks++) {
#pragma unroll
    for (int j = 0; j < 4; j++) bfr[ks][j] = *(const shortx8*)&sctxT[j * 16 + frow][ks * 32 + fk];
    kfr[ks] = *(const shortx8*)&sks[ks * 32 + fk];
  }
  floatx4 acc[2][4] = {};
  floatx4 accd[2] = {};
#pragma unroll
  for (int i = 0; i < 2; i++) {
#pragma unroll
    for (int ks = 0; ks < 2; ks++) {
      const int srow = s0 + i * 16 + frow;
      const bf16* ap = phiQ + ((size_t)srow * 4 + b) * 1024 + h * 64 + ks * 32 + fk;
      shortx8 af = *(const shortx8*)ap;
#pragma unroll
      for (int j = 0; j < 4; j++) acc[i][j] = MFMA16(af, bfr[ks][j], acc[i][j]);
      accd[i] = MFMA16(af, kfr[ks], accd[i]);
    }
  }
#pragma unroll
  for (int i = 0; i < 2; i++) {
#pragma unroll
    for (int r = 0; r < 4; r++) {
      const int srow = s0 + i * 16 + ((lane >> 4) << 2) + r;
      const float den = accd[i][r] + 1e-6f;
#pragma unroll
      for (int j = 0; j < 4; j++) {
        const int e = j * 16 + (lane & 15);
        attn[((size_t)srow * 4 + b) * 1024 + h * 64 + e] = __float2bfloat16(acc[i][j][r] / den);
      }
    }
  }
}

// ---------------------------------------------------------------------------
// layernorm over D=1024: block per row, 256 threads x float4.
// writes fp32 always; bf16 copy if outb != nullptr.
// ---------------------------------------------------------------------------
__global__ __launch_bounds__(256) void ln_kernel(const float* __restrict__ x,
                                                 const float* __restrict__ g,
                                                 const float* __restrict__ be,
                                                 float* __restrict__ outf,
                                                 bf16* __restrict__ outb) {
  const int row = blockIdx.x, t = threadIdx.x;
  const float4 v = ((const float4*)(x + (size_t)row * 1024))[t];
  float s = v.x + v.y + v.z + v.w;
  float q = v.x * v.x + v.y * v.y + v.z * v.z + v.w * v.w;
#pragma unroll
  for (int off = 32; off; off >>= 1) {
    s += __shfl_xor(s, off);
    q += __shfl_xor(q, off);
  }
  __shared__ float ss[4], sq[4];
  const int wave = t >> 6;
  if ((t & 63) == 0) { ss[wave] = s; sq[wave] = q; }
  __syncthreads();
  s = ss[0] + ss[1] + ss[2] + ss[3];
  q = sq[0] + sq[1] + sq[2] + sq[3];
  const float mu = s * (1.f / 1024.f);
  const float var = q * (1.f / 1024.f) - mu * mu;
  const float rstd = rsqrtf(var + 1e-5f);
  const float4 gv = ((const float4*)g)[t];
  const float4 bv = ((const float4*)be)[t];
  float4 y;
  y.x = (v.x - mu) * rstd * gv.x + bv.x;
  y.y = (v.y - mu) * rstd * gv.y + bv.y;
  y.z = (v.z - mu) * rstd * gv.z + bv.z;
  y.w = (v.w - mu) * rstd * gv.w + bv.w;
  ((float4*)(outf + (size_t)row * 1024))[t] = y;
  if (outb != nullptr) {
    bf16 h0 = __float2bfloat16(y.x), h1 = __float2bfloat16(y.y);
    bf16 h2 = __float2bfloat16(y.z), h3 = __float2bfloat16(y.w);
    ushort4 u;
    u.x = __builtin_bit_cast(unsigned short, h0);
    u.y = __builtin_bit_cast(unsigned short, h1);
    u.z = __builtin_bit_cast(unsigned short, h2);
    u.w = __builtin_bit_cast(unsigned short, h3);
    ((ushort4*)(outb + (size_t)row * 1024))[t] = u;
  }
}

// ---------------------------------------------------------------------------
extern "C" void kernel_launch(void* const* d_in, const int* in_sizes, int n_in,
                              void* d_out, int out_size, void* d_ws, size_t ws_size,
                              hipStream_t stream) {
  const float* src = (const float*)d_in[0];
  const float* Wq = (const float*)d_in[1];
  const float* bq = (const float*)d_in[2];
  const float* Wk = (const float*)d_in[3];
  const float* bk = (const float*)d_in[4];
  const float* Wv = (const float*)d_in[5];
  const float* bv = (const float*)d_in[6];
  const float* Wo = (const float*)d_in[7];
  const float* bo = (const float*)d_in[8];
  const float* W1 = (const float*)d_in[9];
  const float* b1 = (const float*)d_in[10];
  const float* W2 = (const float*)d_in[11];
  const float* b2 = (const float*)d_in[12];
  const float* g1 = (const float*)d_in[13];
  const float* be1 = (const float*)d_in[14];
  const float* g2 = (const float*)d_in[15];
  const float* be2 = (const float*)d_in[16];

  const size_t MB = 1024 * 1024;
  char* w = (char*)d_ws;
  // region reuse: [0,64MB): src_bf -> x1 -> x2 ; phiK region -> attn ; V region -> out1b
  bf16* src_bf = (bf16*)(w + 0);          // 32 MB, dead after QKV GEMMs
  float* x1 = (float*)(w + 0);            // 64 MB (src + attn@Wo), dead after LN1
  float* x2 = (float*)(w + 0);            // 64 MB (out1 + ffn), dead after LN2
  bf16* phiQ = (bf16*)(w + 64 * MB);      // 32 MB
  bf16* phiK = (bf16*)(w + 96 * MB);      // 32 MB, dead after ctx
  bf16* attn = (bf16*)(w + 96 * MB);      // 32 MB
  bf16* Vb = (bf16*)(w + 128 * MB);       // 32 MB, dead after ctx
  bf16* out1b = (bf16*)(w + 128 * MB);    // 32 MB
  float* out1f = (float*)(w + 160 * MB);  // 64 MB
  bf16* Wq_b = (bf16*)(w + 224 * MB);
  bf16* Wk_b = (bf16*)(w + 226 * MB);
  bf16* Wv_b = (bf16*)(w + 228 * MB);
  bf16* Wo_b = (bf16*)(w + 230 * MB);
  bf16* W1_b = (bf16*)(w + 232 * MB);
  bf16* W2_b = (bf16*)(w + 236 * MB);
  float* ctx = (float*)(w + 240 * MB);    // 64*64*64 fp32 = 1 MB
  float* ksum = (float*)(w + 241 * MB);   // 4096 fp32
  bf16* H1 = (bf16*)d_out;                // 16384x2048 bf16 = 64 MB scratch in d_out
  float* outf = (float*)d_out;

  const dim3 blk(256);
  // converts
  f2b_kernel<<<16384, blk, 0, stream>>>(src, src_bf, 16777216);
  f2b_kernel<<<1024, blk, 0, stream>>>(Wq, Wq_b, 1048576);
  f2b_kernel<<<1024, blk, 0, stream>>>(Wk, Wk_b, 1048576);
  f2b_kernel<<<1024, blk, 0, stream>>>(Wv, Wv_b, 1048576);
  f2b_kernel<<<1024, blk, 0, stream>>>(Wo, Wo_b, 1048576);
  f2b_kernel<<<2048, blk, 0, stream>>>(W1, W1_b, 2097152);
  f2b_kernel<<<2048, blk, 0, stream>>>(W2, W2_b, 2097152);
  hipMemsetAsync(ctx, 0, (64 * 64 * 64 + 64 * 64) * sizeof(float), stream);

  const dim3 g1024(128, 8), g2048(128, 16);
  // QKV projections with fused phi
  gemm_nt<0><<<g1024, blk, 0, stream>>>(src_bf, Wq_b, bq, nullptr, phiQ, 1024, 1024);
  gemm_nt<0><<<g1024, blk, 0, stream>>>(src_bf, Wk_b, bk, nullptr, phiK, 1024, 1024);
  gemm_nt<1><<<g1024, blk, 0, stream>>>(src_bf, Wv_b, bv, nullptr, Vb, 1024, 1024);
  // linear attention
  ctx_kernel<<<dim3(64, 8), blk, 0, stream>>>(phiK, Vb, ctx, ksum);
  attn_mfma<<<dim3(64, 32), blk, 0, stream>>>(phiQ, ctx, ksum, attn);
  // out projection + residual(src)
  gemm_nt<3><<<g1024, blk, 0, stream>>>(attn, Wo_b, bo, src, x1, 1024, 1024);
  ln_kernel<<<16384, blk, 0, stream>>>(x1, g1, be1, out1f, out1b);
  // FFN
  gemm_nt<2><<<g2048, blk, 0, stream>>>(out1b, W1_b, b1, nullptr, H1, 2048, 1024);
  gemm_nt<3><<<g1024, blk, 0, stream>>>(H1, W2_b, b2, out1f, x2, 1024, 2048);
  ln_kernel<<<16384, blk, 0, stream>>>(x2, g2, be2, outf, nullptr);
}

// Round 2
// 695.520 us; speedup vs baseline: 1.2389x; 1.2389x over previous
//
#include <hip/hip_runtime.h>
#include <hip/hip_bf16.h>

typedef __hip_bfloat16 bf16;
typedef __attribute__((ext_vector_type(4))) float floatx4;
typedef __attribute__((ext_vector_type(8))) short shortx8;

#define MFMA16(a, b, c) __builtin_amdgcn_mfma_f32_16x16x32_bf16(a, b, c, 0, 0, 0)

// async global->LDS, 16 B per lane. lptr must be wave-uniform base + lane*16
// (ours is: per-wave 1024-B slab, lane offset == lane*16).
__device__ __forceinline__ void gll16(const bf16* g, void* l) {
  __builtin_amdgcn_global_load_lds((const __attribute__((address_space(1))) unsigned int*)g,
                                   (__attribute__((address_space(3))) unsigned int*)l,
                                   16, 0, 0);
}

// ---------------------------------------------------------------------------
// fp32 -> bf16 convert, 4 elems/thread, n % 1024 == 0
// ---------------------------------------------------------------------------
__global__ __launch_bounds__(256) void f2b_kernel(const float* __restrict__ in,
                                                  bf16* __restrict__ out, int n) {
  int i = (blockIdx.x * 256 + threadIdx.x) * 4;
  if (i < n) {
    float4 v = *(const float4*)(in + i);
    bf16 h0 = __float2bfloat16(v.x), h1 = __float2bfloat16(v.y);
    bf16 h2 = __float2bfloat16(v.z), h3 = __float2bfloat16(v.w);
    ushort4 u;
    u.x = __builtin_bit_cast(unsigned short, h0);
    u.y = __builtin_bit_cast(unsigned short, h1);
    u.z = __builtin_bit_cast(unsigned short, h2);
    u.w = __builtin_bit_cast(unsigned short, h3);
    *(ushort4*)(out + i) = u;
  }
}

// ---------------------------------------------------------------------------
// NT GEMM: C[n,m] = A[n,:] . W[m,:]  (A [N,K] bf16, W [M,K] bf16, both K-major)
// 128x128 tile, 4 waves (2x2), each wave 64x64 via 4x4 of 16x16x32 MFMA.
// m97 structure: global_load_lds width-16 staging, 2-barrier K-loop.
// EPI: 0 = phi(x)=elu(x)+1 -> bf16 ; 1 = identity -> bf16 ;
//      2 = relu -> bf16 ; 3 = + residual(fp32) -> fp32
// ---------------------------------------------------------------------------
template <int EPI>
__global__ __launch_bounds__(256, 2) void gemm_nt(const bf16* __restrict__ A,
                                                  const bf16* __restrict__ Bw,
                                                  const float* __restrict__ bias,
                                                  const float* __restrict__ res,
                                                  void* __restrict__ outp,
                                                  const int M, const int K) {
  __shared__ __align__(16) bf16 sA[128][32];
  __shared__ __align__(16) bf16 sB[128][32];
  const int tid = threadIdx.x;
  const int lane = tid & 63, wave = tid >> 6;
  const int wm = wave & 1, wn = wave >> 1;
  const int bm = blockIdx.x, bn = blockIdx.y;
  floatx4 acc[4][4] = {};
  const int ar = tid >> 2;         // 0..63 staging row
  const int ak = (tid & 3) << 3;   // 0,8,16,24 staging k
  const bf16* Ab = A + (size_t)(bm * 128 + ar) * K + ak;
  const bf16* Bb = Bw + (size_t)(bn * 128 + ar) * K + ak;
  char* sAc = (char*)sA;
  char* sBc = (char*)sB;
  const int woff = wave * 1024;    // wave-uniform LDS slab base
  const int frow = lane & 15, fk = (lane >> 4) << 3;

  for (int k0 = 0; k0 < K; k0 += 32) {
    __syncthreads();  // previous tile fully consumed
    gll16(Ab + k0, sAc + woff);
    gll16(Ab + (size_t)64 * K + k0, sAc + 4096 + woff);
    gll16(Bb + k0, sBc + woff);
    gll16(Bb + (size_t)64 * K + k0, sBc + 4096 + woff);
    __syncthreads();  // drains vmcnt -> LDS tile visible
    shortx8 af[4], bfr[4];
#pragma unroll
    for (int i = 0; i < 4; i++) af[i] = *(const shortx8*)&sA[wm * 64 + i * 16 + frow][fk];
#pragma unroll
    for (int j = 0; j < 4; j++) bfr[j] = *(const shortx8*)&sB[wn * 64 + j * 16 + frow][fk];
#pragma unroll
    for (int i = 0; i < 4; i++)
#pragma unroll
      for (int j = 0; j < 4; j++)
        acc[i][j] = MFMA16(af[i], bfr[j], acc[i][j]);
  }

  const int row0 = bm * 128 + wm * 64 + ((lane >> 4) << 2);
  const int col0 = bn * 128 + wn * 64 + (lane & 15);
#pragma unroll
  for (int j = 0; j < 4; j++) {
    const int col = col0 + j * 16;
    const float bj = bias[col];
#pragma unroll
    for (int i = 0; i < 4; i++) {
#pragma unroll
      for (int r = 0; r < 4; r++) {
        const int row = row0 + i * 16 + r;
        const size_t o = (size_t)row * M + col;
        float v = acc[i][j][r] + bj;
        if (EPI == 0) {
          v = v > 0.f ? v + 1.f : __expf(v);
          ((bf16*)outp)[o] = __float2bfloat16(v);
        } else if (EPI == 1) {
          ((bf16*)outp)[o] = __float2bfloat16(v);
        } else if (EPI == 2) {
          ((bf16*)outp)[o] = __float2bfloat16(fmaxf(v, 0.f));
        } else {
          ((float*)outp)[o] = v + res[o];
        }
      }
    }
  }
}

// ---------------------------------------------------------------------------
// context via MFMA: ctx[bh,d,e] = sum_s phiK[s,b,h*64+d] * V[s,b,h*64+e]
//                   ksum[bh,d]  = sum_s phiK[s,b,h*64+d]  (ones-B MFMA)
// grid (64 bh, 8 s-chunks of 512), block 256 = 4 waves, each wave a 16x64
// d-strip. phiK/V staged TRANSPOSED into LDS (s-contiguous rows) so both
// A and B fragments are b128 reads along k=s. fp32 atomics into zeroed ws.
// ---------------------------------------------------------------------------
__global__ __launch_bounds__(256) void ctx_mfma(const bf16* __restrict__ phiK,
                                                const bf16* __restrict__ V,
                                                float* __restrict__ ctx,
                                                float* __restrict__ ksum) {
  __shared__ __align__(16) short sKT[64][72];  // [d][s], stride 144 B (16B-mult)
  __shared__ __align__(16) short sVT[64][72];  // [e][s]
  const int bh = blockIdx.x, b = bh >> 4, h = bh & 15;
  const int t = threadIdx.x, lane = t & 63, wave = t >> 6;
  const int s_l = t >> 2;          // 0..63
  const int c0 = (t & 3) << 4;     // 0,16,32,48
  const int frow = lane & 15, fk = (lane >> 4) << 3;
  const shortx8 ones = (shortx8)(short)0x3F80;  // bf16 1.0 splat
  floatx4 acc[4] = {};
  floatx4 accK = {};

  const int sbeg = blockIdx.y * 512;
  for (int sub = 0; sub < 8; sub++) {
    const size_t g = ((size_t)(sbeg + sub * 64 + s_l) * 4 + b) * 1024 + h * 64 + c0;
    shortx8 kv0 = *(const shortx8*)(phiK + g);
    shortx8 kv1 = *(const shortx8*)(phiK + g + 8);
    shortx8 vv0 = *(const shortx8*)(V + g);
    shortx8 vv1 = *(const shortx8*)(V + g + 8);
    __syncthreads();  // previous subtile consumed
#pragma unroll
    for (int j = 0; j < 8; j++) {
      sKT[c0 + j][s_l] = kv0[j];
      sKT[c0 + 8 + j][s_l] = kv1[j];
      sVT[c0 + j][s_l] = vv0[j];
      sVT[c0 + 8 + j][s_l] = vv1[j];
    }
    __syncthreads();
#pragma unroll
    for (int ks = 0; ks < 2; ks++) {
      shortx8 af = *(const shortx8*)&sKT[wave * 16 + frow][ks * 32 + fk];
      accK = MFMA16(af, ones, accK);
#pragma unroll
      for (int j = 0; j < 4; j++) {
        shortx8 bfr = *(const shortx8*)&sVT[j * 16 + frow][ks * 32 + fk];
        acc[j] = MFMA16(af, bfr, acc[j]);
      }
    }
  }

  float* cdst = ctx + (size_t)bh * 4096;
  const int dr0 = wave * 16 + ((lane >> 4) << 2);  // C-layout row base -> d
  const int e = lane & 15;                         // C-layout col -> e offset
#pragma unroll
  for (int j = 0; j < 4; j++)
#pragma unroll
    for (int r = 0; r < 4; r++)
      atomicAdd(cdst + (size_t)(dr0 + r) * 64 + j * 16 + e, acc[j][r]);
  if (e == 0) {
#pragma unroll
    for (int r = 0; r < 4; r++) atomicAdd(ksum + bh * 64 + dr0 + r, accK[r]);
  }
}

// ---------------------------------------------------------------------------
// apply: out[s,b,h*64+e] = (sum_d phiQ[s,d]*ctx[d,e]) / (sum_d phiQ[s,d]*ksum[d] + eps)
// ---------------------------------------------------------------------------
__global__ __launch_bounds__(256) void attn_mfma(const bf16* __restrict__ phiQ,
                                                 const float* __restrict__ ctx,
                                                 const float* __restrict__ ksum,
                                                 bf16* __restrict__ attn) {
  __shared__ __align__(16) bf16 sctxT[64][72];  // [e][d]
  __shared__ __align__(16) bf16 sks[64];
  const int bh = blockIdx.x, b = bh >> 4, h = bh & 15;
  const int t = threadIdx.x, lane = t & 63, wave = t >> 6;
  const float* cbase = ctx + (size_t)bh * 4096;
  for (int idx = t; idx < 4096; idx += 256) {
    int d = idx >> 6, e = idx & 63;
    sctxT[e][d] = __float2bfloat16(cbase[idx]);
  }
  if (t < 64) sks[t] = __float2bfloat16(ksum[bh * 64 + t]);
  __syncthreads();

  const int s0 = blockIdx.y * 128 + wave * 32;
  const int frow = lane & 15, fk = (lane >> 4) << 3;
  shortx8 bfr[2][4], kfr[2];
#pragma unroll
  for (int ks = 0; ks < 2; ks++) {
#pragma unroll
    for (int j = 0; j < 4; j++) bfr[ks][j] = *(const shortx8*)&sctxT[j * 16 + frow][ks * 32 + fk];
    kfr[ks] = *(const shortx8*)&sks[ks * 32 + fk];
  }
  floatx4 acc[2][4] = {};
  floatx4 accd[2] = {};
#pragma unroll
  for (int i = 0; i < 2; i++) {
#pragma unroll
    for (int ks = 0; ks < 2; ks++) {
      const int srow = s0 + i * 16 + frow;
      const bf16* ap = phiQ + ((size_t)srow * 4 + b) * 1024 + h * 64 + ks * 32 + fk;
      shortx8 af = *(const shortx8*)ap;
#pragma unroll
      for (int j = 0; j < 4; j++) acc[i][j] = MFMA16(af, bfr[ks][j], acc[i][j]);
      accd[i] = MFMA16(af, kfr[ks], accd[i]);
    }
  }
#pragma unroll
  for (int i = 0; i < 2; i++) {
#pragma unroll
    for (int r = 0; r < 4; r++) {
      const int srow = s0 + i * 16 + ((lane >> 4) << 2) + r;
      const float den = accd[i][r] + 1e-6f;
#pragma unroll
      for (int j = 0; j < 4; j++) {
        const int e = j * 16 + (lane & 15);
        attn[((size_t)srow * 4 + b) * 1024 + h * 64 + e] = __float2bfloat16(acc[i][j][r] / den);
      }
    }
  }
}

// ---------------------------------------------------------------------------
// layernorm over D=1024: block per row, 256 threads x float4.
// ---------------------------------------------------------------------------
__global__ __launch_bounds__(256) void ln_kernel(const float* __restrict__ x,
                                                 const float* __restrict__ g,
                                                 const float* __restrict__ be,
                                                 float* __restrict__ outf,
                                                 bf16* __restrict__ outb) {
  const int row = blockIdx.x, t = threadIdx.x;
  const float4 v = ((const float4*)(x + (size_t)row * 1024))[t];
  float s = v.x + v.y + v.z + v.w;
  float q = v.x * v.x + v.y * v.y + v.z * v.z + v.w * v.w;
#pragma unroll
  for (int off = 32; off; off >>= 1) {
    s += __shfl_xor(s, off);
    q += __shfl_xor(q, off);
  }
  __shared__ float ss[4], sq[4];
  const int wave = t >> 6;
  if ((t & 63) == 0) { ss[wave] = s; sq[wave] = q; }
  __syncthreads();
  s = ss[0] + ss[1] + ss[2] + ss[3];
  q = sq[0] + sq[1] + sq[2] + sq[3];
  const float mu = s * (1.f / 1024.f);
  const float var = q * (1.f / 1024.f) - mu * mu;
  const float rstd = rsqrtf(var + 1e-5f);
  const float4 gv = ((const float4*)g)[t];
  const float4 bv = ((const float4*)be)[t];
  float4 y;
  y.x = (v.x - mu) * rstd * gv.x + bv.x;
  y.y = (v.y - mu) * rstd * gv.y + bv.y;
  y.z = (v.z - mu) * rstd * gv.z + bv.z;
  y.w = (v.w - mu) * rstd * gv.w + bv.w;
  ((float4*)(outf + (size_t)row * 1024))[t] = y;
  if (outb != nullptr) {
    bf16 h0 = __float2bfloat16(y.x), h1 = __float2bfloat16(y.y);
    bf16 h2 = __float2bfloat16(y.z), h3 = __float2bfloat16(y.w);
    ushort4 u;
    u.x = __builtin_bit_cast(unsigned short, h0);
    u.y = __builtin_bit_cast(unsigned short, h1);
    u.z = __builtin_bit_cast(unsigned short, h2);
    u.w = __builtin_bit_cast(unsigned short, h3);
    ((ushort4*)(outb + (size_t)row * 1024))[t] = u;
  }
}

// ---------------------------------------------------------------------------
extern "C" void kernel_launch(void* const* d_in, const int* in_sizes, int n_in,
                              void* d_out, int out_size, void* d_ws, size_t ws_size,
                              hipStream_t stream) {
  const float* src = (const float*)d_in[0];
  const float* Wq = (const float*)d_in[1];
  const float* bq = (const float*)d_in[2];
  const float* Wk = (const float*)d_in[3];
  const float* bk = (const float*)d_in[4];
  const float* Wv = (const float*)d_in[5];
  const float* bv = (const float*)d_in[6];
  const float* Wo = (const float*)d_in[7];
  const float* bo = (const float*)d_in[8];
  const float* W1 = (const float*)d_in[9];
  const float* b1 = (const float*)d_in[10];
  const float* W2 = (const float*)d_in[11];
  const float* b2 = (const float*)d_in[12];
  const float* g1 = (const float*)d_in[13];
  const float* be1 = (const float*)d_in[14];
  const float* g2 = (const float*)d_in[15];
  const float* be2 = (const float*)d_in[16];

  const size_t MB = 1024 * 1024;
  char* w = (char*)d_ws;
  bf16* src_bf = (bf16*)(w + 0);          // 32 MB, dead after QKV GEMMs
  float* x1 = (float*)(w + 0);            // 64 MB (src + attn@Wo), dead after LN1
  float* x2 = (float*)(w + 0);            // 64 MB (out1 + ffn), dead after LN2
  bf16* phiQ = (bf16*)(w + 64 * MB);      // 32 MB
  bf16* phiK = (bf16*)(w + 96 * MB);      // 32 MB, dead after ctx
  bf16* attn = (bf16*)(w + 96 * MB);      // 32 MB
  bf16* Vb = (bf16*)(w + 128 * MB);       // 32 MB, dead after ctx
  bf16* out1b = (bf16*)(w + 128 * MB);    // 32 MB
  float* out1f = (float*)(w + 160 * MB);  // 64 MB
  bf16* Wq_b = (bf16*)(w + 224 * MB);
  bf16* Wk_b = (bf16*)(w + 226 * MB);
  bf16* Wv_b = (bf16*)(w + 228 * MB);
  bf16* Wo_b = (bf16*)(w + 230 * MB);
  bf16* W1_b = (bf16*)(w + 232 * MB);
  bf16* W2_b = (bf16*)(w + 236 * MB);
  float* ctx = (float*)(w + 240 * MB);    // 64*64*64 fp32 = 1 MB
  float* ksum = (float*)(w + 241 * MB);   // 4096 fp32
  bf16* H1 = (bf16*)d_out;                // 16384x2048 bf16 = 64 MB scratch in d_out
  float* outf = (float*)d_out;

  const dim3 blk(256);
  f2b_kernel<<<16384, blk, 0, stream>>>(src, src_bf, 16777216);
  f2b_kernel<<<1024, blk, 0, stream>>>(Wq, Wq_b, 1048576);
  f2b_kernel<<<1024, blk, 0, stream>>>(Wk, Wk_b, 1048576);
  f2b_kernel<<<1024, blk, 0, stream>>>(Wv, Wv_b, 1048576);
  f2b_kernel<<<1024, blk, 0, stream>>>(Wo, Wo_b, 1048576);
  f2b_kernel<<<2048, blk, 0, stream>>>(W1, W1_b, 2097152);
  f2b_kernel<<<2048, blk, 0, stream>>>(W2, W2_b, 2097152);
  hipMemsetAsync(ctx, 0, (64 * 64 * 64 + 64 * 64) * sizeof(float), stream);

  const dim3 g1024(128, 8), g2048(128, 16);
  gemm_nt<0><<<g1024, blk, 0, stream>>>(src_bf, Wq_b, bq, nullptr, phiQ, 1024, 1024);
  gemm_nt<0><<<g1024, blk, 0, stream>>>(src_bf, Wk_b, bk, nullptr, phiK, 1024, 1024);
  gemm_nt<1><<<g1024, blk, 0, stream>>>(src_bf, Wv_b, bv, nullptr, Vb, 1024, 1024);
  ctx_mfma<<<dim3(64, 8), blk, 0, stream>>>(phiK, Vb, ctx, ksum);
  attn_mfma<<<dim3(64, 32), blk, 0, stream>>>(phiQ, ctx, ksum, attn);
  gemm_nt<3><<<g1024, blk, 0, stream>>>(attn, Wo_b, bo, src, x1, 1024, 1024);
  ln_kernel<<<16384, blk, 0, stream>>>(x1, g1, be1, out1f, out1b);
  gemm_nt<2><<<g2048, blk, 0, stream>>>(out1b, W1_b, b1, nullptr, H1, 2048, 1024);
  gemm_nt<3><<<g1024, blk, 0, stream>>>(H1, W2_b, b2, out1f, x2, 1024, 2048);
  ln_kernel<<<16384, blk, 0, stream>>>(x2, g2, be2, outf, nullptr);
}

// Round 3
// 676.417 us; speedup vs baseline: 1.2739x; 1.0282x over previous
//
#include <hip/hip_runtime.h>
#include <hip/hip_bf16.h>

typedef __hip_bfloat16 bf16;
typedef __attribute__((ext_vector_type(4))) float floatx4;
typedef __attribute__((ext_vector_type(8))) short shortx8;

#define MFMA16(a, b, c) __builtin_amdgcn_mfma_f32_16x16x32_bf16(a, b, c, 0, 0, 0)

// async global->LDS, 16 B per lane. lptr must be wave-uniform base + lane*16
// (ours is: per-wave 1024-B slab, lane offset == lane*16).
__device__ __forceinline__ void gll16(const bf16* g, void* l) {
  __builtin_amdgcn_global_load_lds((const __attribute__((address_space(1))) unsigned int*)g,
                                   (__attribute__((address_space(3))) unsigned int*)l,
                                   16, 0, 0);
}

// ---------------------------------------------------------------------------
// fp32 -> bf16 convert, 4 elems/thread, n % 1024 == 0
// ---------------------------------------------------------------------------
__global__ __launch_bounds__(256) void f2b_kernel(const float* __restrict__ in,
                                                  bf16* __restrict__ out, int n) {
  int i = (blockIdx.x * 256 + threadIdx.x) * 4;
  if (i < n) {
    float4 v = *(const float4*)(in + i);
    bf16 h0 = __float2bfloat16(v.x), h1 = __float2bfloat16(v.y);
    bf16 h2 = __float2bfloat16(v.z), h3 = __float2bfloat16(v.w);
    ushort4 u;
    u.x = __builtin_bit_cast(unsigned short, h0);
    u.y = __builtin_bit_cast(unsigned short, h1);
    u.z = __builtin_bit_cast(unsigned short, h2);
    u.w = __builtin_bit_cast(unsigned short, h3);
    *(ushort4*)(out + i) = u;
  }
}

// ---------------------------------------------------------------------------
// NT GEMM: C[n,m] = A[n,:] . W[m,:]  (A [N,K] bf16, W [M,K] bf16, both K-major)
// 128x128 tile, 4 waves (2x2), each wave 64x64 via 4x4 of 16x16x32 MFMA.
// m97 structure: global_load_lds width-16 staging, 2-barrier K-loop.
// LDS XOR swizzle: global k-chunk q of row r lives at LDS chunk q^((r>>1)&3).
// global_load_lds pins LDS dest to lane*16, so the swizzle is implemented by
// permuting WHICH global chunk each staging lane fetches (coalescing intact:
// the 4 lanes of a row still cover the same 64B segment). Fragment ds_read_b128
// then lands 2-way banked (free, m136) instead of 8-way (2.94x, round-2 PMC:
// 8.4M SQ_LDS_BANK_CONFLICT).
// EPI: 0 = phi(x)=elu(x)+1 -> bf16 ; 1 = identity -> bf16 ;
//      2 = relu -> bf16 ; 3 = + residual(fp32) -> fp32
// ---------------------------------------------------------------------------
template <int EPI>
__global__ __launch_bounds__(256, 2) void gemm_nt(const bf16* __restrict__ A,
                                                  const bf16* __restrict__ Bw,
                                                  const float* __restrict__ bias,
                                                  const float* __restrict__ res,
                                                  void* __restrict__ outp,
                                                  const int M, const int K) {
  __shared__ __align__(16) bf16 sA[128][32];
  __shared__ __align__(16) bf16 sB[128][32];
  const int tid = threadIdx.x;
  const int lane = tid & 63, wave = tid >> 6;
  const int wm = wave & 1, wn = wave >> 1;
  const int bm = blockIdx.x, bn = blockIdx.y;
  floatx4 acc[4][4] = {};
  const int ar = tid >> 2;                              // 0..63 staging row
  const int aks = (((tid & 3) ^ ((ar >> 1) & 3))) << 3; // swizzled k-offset (bf16)
  const bf16* Ab = A + (size_t)(bm * 128 + ar) * K + aks;
  const bf16* Bb = Bw + (size_t)(bn * 128 + ar) * K + aks;
  char* sAc = (char*)sA;
  char* sBc = (char*)sB;
  const int woff = wave * 1024;    // wave-uniform LDS slab base
  const int frow = lane & 15;
  const int fks = (((lane >> 4) ^ ((frow >> 1) & 3))) << 3;  // swizzled LDS chunk

  for (int k0 = 0; k0 < K; k0 += 32) {
    __syncthreads();  // previous tile fully consumed
    gll16(Ab + k0, sAc + woff);
    gll16(Ab + (size_t)64 * K + k0, sAc + 4096 + woff);
    gll16(Bb + k0, sBc + woff);
    gll16(Bb + (size_t)64 * K + k0, sBc + 4096 + woff);
    __syncthreads();  // drains vmcnt -> LDS tile visible
    shortx8 af[4], bfr[4];
#pragma unroll
    for (int i = 0; i < 4; i++) af[i] = *(const shortx8*)&sA[wm * 64 + i * 16 + frow][fks];
#pragma unroll
    for (int j = 0; j < 4; j++) bfr[j] = *(const shortx8*)&sB[wn * 64 + j * 16 + frow][fks];
#pragma unroll
    for (int i = 0; i < 4; i++)
#pragma unroll
      for (int j = 0; j < 4; j++)
        acc[i][j] = MFMA16(af[i], bfr[j], acc[i][j]);
  }

  const int row0 = bm * 128 + wm * 64 + ((lane >> 4) << 2);
  const int col0 = bn * 128 + wn * 64 + (lane & 15);
#pragma unroll
  for (int j = 0; j < 4; j++) {
    const int col = col0 + j * 16;
    const float bj = bias[col];
#pragma unroll
    for (int i = 0; i < 4; i++) {
#pragma unroll
      for (int r = 0; r < 4; r++) {
        const int row = row0 + i * 16 + r;
        const size_t o = (size_t)row * M + col;
        float v = acc[i][j][r] + bj;
        if (EPI == 0) {
          v = v > 0.f ? v + 1.f : __expf(v);
          ((bf16*)outp)[o] = __float2bfloat16(v);
        } else if (EPI == 1) {
          ((bf16*)outp)[o] = __float2bfloat16(v);
        } else if (EPI == 2) {
          ((bf16*)outp)[o] = __float2bfloat16(fmaxf(v, 0.f));
        } else {
          ((float*)outp)[o] = v + res[o];
        }
      }
    }
  }
}

// ---------------------------------------------------------------------------
// context via MFMA: ctx[bh,d,e] = sum_s phiK[s,b,h*64+d] * V[s,b,h*64+e]
//                   ksum[bh,d]  = sum_s phiK[s,b,h*64+d]  (ones-B MFMA)
// ---------------------------------------------------------------------------
__global__ __launch_bounds__(256) void ctx_mfma(const bf16* __restrict__ phiK,
                                                const bf16* __restrict__ V,
                                                float* __restrict__ ctx,
                                                float* __restrict__ ksum) {
  __shared__ __align__(16) short sKT[64][72];  // [d][s], stride 144 B
  __shared__ __align__(16) short sVT[64][72];  // [e][s]
  const int bh = blockIdx.x, b = bh >> 4, h = bh & 15;
  const int t = threadIdx.x, lane = t & 63, wave = t >> 6;
  const int s_l = t >> 2;          // 0..63
  const int c0 = (t & 3) << 4;     // 0,16,32,48
  const int frow = lane & 15, fk = (lane >> 4) << 3;
  const shortx8 ones = (shortx8)(short)0x3F80;  // bf16 1.0 splat
  floatx4 acc[4] = {};
  floatx4 accK = {};

  const int sbeg = blockIdx.y * 512;
  for (int sub = 0; sub < 8; sub++) {
    const size_t g = ((size_t)(sbeg + sub * 64 + s_l) * 4 + b) * 1024 + h * 64 + c0;
    shortx8 kv0 = *(const shortx8*)(phiK + g);
    shortx8 kv1 = *(const shortx8*)(phiK + g + 8);
    shortx8 vv0 = *(const shortx8*)(V + g);
    shortx8 vv1 = *(const shortx8*)(V + g + 8);
    __syncthreads();  // previous subtile consumed
#pragma unroll
    for (int j = 0; j < 8; j++) {
      sKT[c0 + j][s_l] = kv0[j];
      sKT[c0 + 8 + j][s_l] = kv1[j];
      sVT[c0 + j][s_l] = vv0[j];
      sVT[c0 + 8 + j][s_l] = vv1[j];
    }
    __syncthreads();
#pragma unroll
    for (int ks = 0; ks < 2; ks++) {
      shortx8 af = *(const shortx8*)&sKT[wave * 16 + frow][ks * 32 + fk];
      accK = MFMA16(af, ones, accK);
#pragma unroll
      for (int j = 0; j < 4; j++) {
        shortx8 bfr = *(const shortx8*)&sVT[j * 16 + frow][ks * 32 + fk];
        acc[j] = MFMA16(af, bfr, acc[j]);
      }
    }
  }

  float* cdst = ctx + (size_t)bh * 4096;
  const int dr0 = wave * 16 + ((lane >> 4) << 2);  // C-layout row base -> d
  const int e = lane & 15;                         // C-layout col -> e offset
#pragma unroll
  for (int j = 0; j < 4; j++)
#pragma unroll
    for (int r = 0; r < 4; r++)
      atomicAdd(cdst + (size_t)(dr0 + r) * 64 + j * 16 + e, acc[j][r]);
  if (e == 0) {
#pragma unroll
    for (int r = 0; r < 4; r++) atomicAdd(ksum + bh * 64 + dr0 + r, accK[r]);
  }
}

// ---------------------------------------------------------------------------
// apply: out[s,b,h*64+e] = (sum_d phiQ[s,d]*ctx[d,e]) / (sum_d phiQ[s,d]*ksum[d] + eps)
// ---------------------------------------------------------------------------
__global__ __launch_bounds__(256) void attn_mfma(const bf16* __restrict__ phiQ,
                                                 const float* __restrict__ ctx,
                                                 const float* __restrict__ ksum,
                                                 bf16* __restrict__ attn) {
  __shared__ __align__(16) bf16 sctxT[64][72];  // [e][d]
  __shared__ __align__(16) bf16 sks[64];
  const int bh = blockIdx.x, b = bh >> 4, h = bh & 15;
  const int t = threadIdx.x, lane = t & 63, wave = t >> 6;
  const float* cbase = ctx + (size_t)bh * 4096;
  for (int idx = t; idx < 4096; idx += 256) {
    int d = idx >> 6, e = idx & 63;
    sctxT[e][d] = __float2bfloat16(cbase[idx]);
  }
  if (t < 64) sks[t] = __float2bfloat16(ksum[bh * 64 + t]);
  __syncthreads();

  const int s0 = blockIdx.y * 128 + wave * 32;
  const int frow = lane & 15, fk = (lane >> 4) << 3;
  shortx8 bfr[2][4], kfr[2];
#pragma unroll
  for (int ks = 0; ks < 2; ks++) {
#pragma unroll
    for (int j = 0; j < 4; j++) bfr[ks][j] = *(const shortx8*)&sctxT[j * 16 + frow][ks * 32 + fk];
    kfr[ks] = *(const shortx8*)&sks[ks * 32 + fk];
  }
  floatx4 acc[2][4] = {};
  floatx4 accd[2] = {};
#pragma unroll
  for (int i = 0; i < 2; i++) {
#pragma unroll
    for (int ks = 0; ks < 2; ks++) {
      const int srow = s0 + i * 16 + frow;
      const bf16* ap = phiQ + ((size_t)srow * 4 + b) * 1024 + h * 64 + ks * 32 + fk;
      shortx8 af = *(const shortx8*)ap;
#pragma unroll
      for (int j = 0; j < 4; j++) acc[i][j] = MFMA16(af, bfr[ks][j], acc[i][j]);
      accd[i] = MFMA16(af, kfr[ks], accd[i]);
    }
  }
#pragma unroll
  for (int i = 0; i < 2; i++) {
#pragma unroll
    for (int r = 0; r < 4; r++) {
      const int srow = s0 + i * 16 + ((lane >> 4) << 2) + r;
      const float den = accd[i][r] + 1e-6f;
#pragma unroll
      for (int j = 0; j < 4; j++) {
        const int e = j * 16 + (lane & 15);
        attn[((size_t)srow * 4 + b) * 1024 + h * 64 + e] = __float2bfloat16(acc[i][j][r] / den);
      }
    }
  }
}

// ---------------------------------------------------------------------------
// layernorm over D=1024: block per row, 256 threads x float4.
// ---------------------------------------------------------------------------
__global__ __launch_bounds__(256) void ln_kernel(const float* __restrict__ x,
                                                 const float* __restrict__ g,
                                                 const float* __restrict__ be,
                                                 float* __restrict__ outf,
                                                 bf16* __restrict__ outb) {
  const int row = blockIdx.x, t = threadIdx.x;
  const float4 v = ((const float4*)(x + (size_t)row * 1024))[t];
  float s = v.x + v.y + v.z + v.w;
  float q = v.x * v.x + v.y * v.y + v.z * v.z + v.w * v.w;
#pragma unroll
  for (int off = 32; off; off >>= 1) {
    s += __shfl_xor(s, off);
    q += __shfl_xor(q, off);
  }
  __shared__ float ss[4], sq[4];
  const int wave = t >> 6;
  if ((t & 63) == 0) { ss[wave] = s; sq[wave] = q; }
  __syncthreads();
  s = ss[0] + ss[1] + ss[2] + ss[3];
  q = sq[0] + sq[1] + sq[2] + sq[3];
  const float mu = s * (1.f / 1024.f);
  const float var = q * (1.f / 1024.f) - mu * mu;
  const float rstd = rsqrtf(var + 1e-5f);
  const float4 gv = ((const float4*)g)[t];
  const float4 bv = ((const float4*)be)[t];
  float4 y;
  y.x = (v.x - mu) * rstd * gv.x + bv.x;
  y.y = (v.y - mu) * rstd * gv.y + bv.y;
  y.z = (v.z - mu) * rstd * gv.z + bv.z;
  y.w = (v.w - mu) * rstd * gv.w + bv.w;
  ((float4*)(outf + (size_t)row * 1024))[t] = y;
  if (outb != nullptr) {
    bf16 h0 = __float2bfloat16(y.x), h1 = __float2bfloat16(y.y);
    bf16 h2 = __float2bfloat16(y.z), h3 = __float2bfloat16(y.w);
    ushort4 u;
    u.x = __builtin_bit_cast(unsigned short, h0);
    u.y = __builtin_bit_cast(unsigned short, h1);
    u.z = __builtin_bit_cast(unsigned short, h2);
    u.w = __builtin_bit_cast(unsigned short, h3);
    ((ushort4*)(outb + (size_t)row * 1024))[t] = u;
  }
}

// ---------------------------------------------------------------------------
extern "C" void kernel_launch(void* const* d_in, const int* in_sizes, int n_in,
                              void* d_out, int out_size, void* d_ws, size_t ws_size,
                              hipStream_t stream) {
  const float* src = (const float*)d_in[0];
  const float* Wq = (const float*)d_in[1];
  const float* bq = (const float*)d_in[2];
  const float* Wk = (const float*)d_in[3];
  const float* bk = (const float*)d_in[4];
  const float* Wv = (const float*)d_in[5];
  const float* bv = (const float*)d_in[6];
  const float* Wo = (const float*)d_in[7];
  const float* bo = (const float*)d_in[8];
  const float* W1 = (const float*)d_in[9];
  const float* b1 = (const float*)d_in[10];
  const float* W2 = (const float*)d_in[11];
  const float* b2 = (const float*)d_in[12];
  const float* g1 = (const float*)d_in[13];
  const float* be1 = (const float*)d_in[14];
  const float* g2 = (const float*)d_in[15];
  const float* be2 = (const float*)d_in[16];

  const size_t MB = 1024 * 1024;
  char* w = (char*)d_ws;
  bf16* src_bf = (bf16*)(w + 0);          // 32 MB, dead after QKV GEMMs
  float* x1 = (float*)(w + 0);            // 64 MB (src + attn@Wo), dead after LN1
  float* x2 = (float*)(w + 0);            // 64 MB (out1 + ffn), dead after LN2
  bf16* phiQ = (bf16*)(w + 64 * MB);      // 32 MB
  bf16* phiK = (bf16*)(w + 96 * MB);      // 32 MB, dead after ctx
  bf16* attn = (bf16*)(w + 96 * MB);      // 32 MB
  bf16* Vb = (bf16*)(w + 128 * MB);       // 32 MB, dead after ctx
  bf16* out1b = (bf16*)(w + 128 * MB);    // 32 MB
  float* out1f = (float*)(w + 160 * MB);  // 64 MB
  bf16* Wq_b = (bf16*)(w + 224 * MB);
  bf16* Wk_b = (bf16*)(w + 226 * MB);
  bf16* Wv_b = (bf16*)(w + 228 * MB);
  bf16* Wo_b = (bf16*)(w + 230 * MB);
  bf16* W1_b = (bf16*)(w + 232 * MB);
  bf16* W2_b = (bf16*)(w + 236 * MB);
  float* ctx = (float*)(w + 240 * MB);    // 64*64*64 fp32 = 1 MB
  float* ksum = (float*)(w + 241 * MB);   // 4096 fp32
  bf16* H1 = (bf16*)d_out;                // 16384x2048 bf16 = 64 MB scratch in d_out
  float* outf = (float*)d_out;

  const dim3 blk(256);
  f2b_kernel<<<16384, blk, 0, stream>>>(src, src_bf, 16777216);
  f2b_kernel<<<1024, blk, 0, stream>>>(Wq, Wq_b, 1048576);
  f2b_kernel<<<1024, blk, 0, stream>>>(Wk, Wk_b, 1048576);
  f2b_kernel<<<1024, blk, 0, stream>>>(Wv, Wv_b, 1048576);
  f2b_kernel<<<1024, blk, 0, stream>>>(Wo, Wo_b, 1048576);
  f2b_kernel<<<2048, blk, 0, stream>>>(W1, W1_b, 2097152);
  f2b_kernel<<<2048, blk, 0, stream>>>(W2, W2_b, 2097152);
  hipMemsetAsync(ctx, 0, (64 * 64 * 64 + 64 * 64) * sizeof(float), stream);

  const dim3 g1024(128, 8), g2048(128, 16);
  gemm_nt<0><<<g1024, blk, 0, stream>>>(src_bf, Wq_b, bq, nullptr, phiQ, 1024, 1024);
  gemm_nt<0><<<g1024, blk, 0, stream>>>(src_bf, Wk_b, bk, nullptr, phiK, 1024, 1024);
  gemm_nt<1><<<g1024, blk, 0, stream>>>(src_bf, Wv_b, bv, nullptr, Vb, 1024, 1024);
  ctx_mfma<<<dim3(64, 8), blk, 0, stream>>>(phiK, Vb, ctx, ksum);
  attn_mfma<<<dim3(64, 32), blk, 0, stream>>>(phiQ, ctx, ksum, attn);
  gemm_nt<3><<<g1024, blk, 0, stream>>>(attn, Wo_b, bo, src, x1, 1024, 1024);
  ln_kernel<<<16384, blk, 0, stream>>>(x1, g1, be1, out1f, out1b);
  gemm_nt<2><<<g2048, blk, 0, stream>>>(out1b, W1_b, b1, nullptr, H1, 2048, 1024);
  gemm_nt<3><<<g1024, blk, 0, stream>>>(H1, W2_b, b2, out1f, x2, 1024, 2048);
  ln_kernel<<<16384, blk, 0, stream>>>(x2, g2, be2, outf, nullptr);
}